// Round 26
// baseline (151.706 us; speedup 1.0000x reference)
//
#include <hip/hip_runtime.h>

#define B_ 4
#define T_ 2048
#define D_ 1024
#define H_ 16
#define DH_ 64
#define BH_ (B_*H_)   // 64
#define M_ (B_*T_)    // 8192
#define N3_ (3*D_)    // 3072

typedef __attribute__((ext_vector_type(8))) __bf16 bf16x8;
typedef __attribute__((ext_vector_type(4))) float f32x4;
typedef __attribute__((ext_vector_type(16))) float f32x16;
typedef __attribute__((ext_vector_type(8))) unsigned short u16x8;
typedef __attribute__((ext_vector_type(4))) unsigned short u16x4;
typedef int i32x2 __attribute__((ext_vector_type(2)));

__device__ inline void gload_lds16(const void* g, void* l) {
  __builtin_amdgcn_global_load_lds((const __attribute__((address_space(1))) void*)g,
                                   (__attribute__((address_space(3))) void*)l, 16, 0, 0);
}

__device__ inline unsigned short f2bf(float v) {
  __bf16 t = (__bf16)v;
  return *(unsigned short*)&t;
}

__device__ inline float bf2f(unsigned short u) {
  unsigned x = ((unsigned)u) << 16;
  return __builtin_bit_cast(float, x);
}

__device__ inline unsigned pk2(float lo, float hi2) {
  return (unsigned)f2bf(lo) | ((unsigned)f2bf(hi2) << 16);
}

// Build PV B-fragment (P^T[16k][32q]); permlane32_swap: dst.row1 <-> src.row0 (verified r12).
template<int BASE>
__device__ inline bf16x8 buildP(const f32x16& S) {
  unsigned a = pk2(S[BASE+0], S[BASE+1]);
  unsigned b = pk2(S[BASE+2], S[BASE+3]);
  unsigned c = pk2(S[BASE+4], S[BASE+5]);
  unsigned d = pk2(S[BASE+6], S[BASE+7]);
  i32x2 r0 = __builtin_amdgcn_permlane32_swap((int)a, (int)c, false, false);
  i32x2 r1 = __builtin_amdgcn_permlane32_swap((int)b, (int)d, false, false);
  union { unsigned u[4]; bf16x8 v; } U;
  U.u[0] = (unsigned)r0[0];
  U.u[1] = (unsigned)r1[0];
  U.u[2] = (unsigned)r0[1];
  U.u[3] = (unsigned)r1[1];
  return U.v;
}

// ------------- fused prep: cast x -> bf16 | transpose+cast w_qkv | transpose+cast w_out ----
__global__ void prep(const float* __restrict__ x, unsigned short* __restrict__ xb,
                     const float* __restrict__ wq, unsigned short* __restrict__ wqT,
                     const float* __restrict__ wo, unsigned short* __restrict__ woT) {
  __shared__ unsigned short lds[64][72];
  int bid = blockIdx.x, tid = threadIdx.x;
  if (bid < 4096) {
    int i = bid * 256 + tid;
    const float4* p = (const float4*)(x + (size_t)i * 8);
    float4 a = p[0], b = p[1];
    float v[8] = {a.x, a.y, a.z, a.w, b.x, b.y, b.z, b.w};
    u16x8 r;
#pragma unroll
    for (int j = 0; j < 8; ++j) r[j] = f2bf(v[j]);
    *(u16x8*)(xb + (size_t)i * 8) = r;
    return;
  }
  const float* w;
  unsigned short* wt;
  int n0, k0, Ndim;
  if (bid < 4096 + 768) {
    int b2 = bid - 4096;
    w = wq; wt = wqT; Ndim = N3_;
    n0 = (b2 % 48) * 64; k0 = (b2 / 48) * 64;
  } else {
    int b3 = bid - 4864;
    w = wo; wt = woT; Ndim = D_;
    n0 = (b3 % 16) * 64; k0 = (b3 / 16) * 64;
  }
#pragma unroll
  for (int i = 0; i < 2; ++i) {
    int idx = i * 256 + tid;
    int r = idx >> 3, c8 = idx & 7;
    const float4* src = (const float4*)(w + (size_t)(k0 + r) * Ndim + n0 + c8 * 8);
    float4 a = src[0], b = src[1];
    float v[8] = {a.x, a.y, a.z, a.w, b.x, b.y, b.z, b.w};
#pragma unroll
    for (int j = 0; j < 8; ++j) lds[r][c8 * 8 + j] = f2bf(v[j]);
  }
  __syncthreads();
#pragma unroll
  for (int i = 0; i < 2; ++i) {
    int idx = i * 256 + tid;
    int r = idx >> 3, c8 = idx & 7;
    u16x8 o;
#pragma unroll
    for (int j = 0; j < 8; ++j) o[j] = lds[c8 * 8 + j][r];
    *(u16x8*)(wt + (size_t)(n0 + r) * 1024 + k0 + c8 * 8) = o;
  }
}

// ------------- pipelined GEMM: 128x128 tile, BK=64, 4 waves, 2-slot ring, vmcnt(8),
// XCD slab swizzle, K-loop fully unrolled ----
__global__ __launch_bounds__(256) void gemm2b(
    const unsigned short* __restrict__ A,
    const unsigned short* __restrict__ BT,
    int epi,
    unsigned short* __restrict__ qb, unsigned short* __restrict__ kb, unsigned short* __restrict__ vtb,
    float* __restrict__ outf) {
  extern __shared__ __align__(16) char lds[];   // 2 * 32768 = 65536 bytes
  const int tid = threadIdx.x;
  const int wave = tid >> 6, lane = tid & 63, g = lane >> 4, c = lane & 15;
  const int wm = wave >> 1, wn = wave & 1;
  int flat = blockIdx.y * gridDim.x + blockIdx.x;
  int xcd = flat & 7, local = flat >> 3;
  int bx = xcd * 8 + (local & 7);   // gridDim.x == 64
  int by = local >> 3;
  const int m0 = bx * 128, n0 = by * 128;

  f32x4 acc[4][4] = {};

  auto stage = [&](int slot, int jj) {
    char* sb = lds + slot * 32768;
#pragma unroll
    for (int i = 0; i < 4; ++i) {
      int idx = i * 256 + tid;
      int r = idx >> 3, s = idx & 7;
      gload_lds16(A + (size_t)(m0 + r) * 1024 + jj * 64 + 8 * (s ^ (r & 7)),
                  sb + idx * 16);
    }
#pragma unroll
    for (int i = 0; i < 4; ++i) {
      int idx = i * 256 + tid;
      int r = idx >> 3, s = idx & 7;
      gload_lds16(BT + (size_t)(n0 + r) * 1024 + jj * 64 + 8 * (s ^ (r & 7)),
                  sb + 16384 + idx * 16);
    }
  };

  stage(0, 0);
#pragma unroll
  for (int j = 0; j < 16; ++j) {
    if (j < 15) {
      stage((j + 1) & 1, j + 1);
      asm volatile("s_waitcnt vmcnt(8)" ::: "memory");
    } else {
      asm volatile("s_waitcnt vmcnt(0)" ::: "memory");
    }
    __builtin_amdgcn_s_barrier();
    asm volatile("" ::: "memory");

    const char* sA = lds + (j & 1) * 32768;
    const char* sB = sA + 16384;
#pragma unroll
    for (int kc = 0; kc < 2; ++kc) {
      bf16x8 af[4], bf[4];
#pragma unroll
      for (int mt = 0; mt < 4; ++mt) {
        int r = wm * 64 + mt * 16 + c;
        af[mt] = *(const bf16x8*)(sA + r * 128 + 16 * ((kc * 4 + g) ^ (r & 7)));
      }
#pragma unroll
      for (int nt = 0; nt < 4; ++nt) {
        int r = wn * 64 + nt * 16 + c;
        bf[nt] = *(const bf16x8*)(sB + r * 128 + 16 * ((kc * 4 + g) ^ (r & 7)));
      }
      __builtin_amdgcn_s_setprio(1);
#pragma unroll
      for (int mt = 0; mt < 4; ++mt)
#pragma unroll
        for (int nt = 0; nt < 4; ++nt)
          acc[mt][nt] = __builtin_amdgcn_mfma_f32_16x16x32_bf16(af[mt], bf[nt], acc[mt][nt], 0, 0, 0);
      __builtin_amdgcn_s_setprio(0);
    }

    __builtin_amdgcn_s_barrier();
    asm volatile("" ::: "memory");
  }

  if (epi == 0) {
    int which = n0 >> 10;  // 0:q 1:k 2:v (uniform: 128 | 1024)
    int colbase = n0 - (which << 10);
    if (which == 2) {
#pragma unroll
      for (int mt = 0; mt < 4; ++mt)
#pragma unroll
        for (int nt = 0; nt < 4; ++nt) {
          int m = m0 + wm * 64 + mt * 16 + g * 4;
          int n = colbase + wn * 64 + nt * 16 + c;
          int b = m >> 11, t = m & 2047;
          int h = n >> 6, d = n & 63;
          u16x4 pk;
#pragma unroll
          for (int i = 0; i < 4; ++i) pk[i] = f2bf(acc[mt][nt][i]);
          *(u16x4*)(vtb + ((size_t)(b * H_ + h) * 64 + d) * T_ + t) = pk;
        }
    } else {
      unsigned short* dst = which == 0 ? qb : kb;
      float scale = which == 0 ? 0.18033688011112042f : 1.0f;  // (1/8)*log2(e)
#pragma unroll
      for (int mt = 0; mt < 4; ++mt)
#pragma unroll
        for (int nt = 0; nt < 4; ++nt)
#pragma unroll
          for (int i = 0; i < 4; ++i) {
            int m = m0 + wm * 64 + mt * 16 + g * 4 + i;
            int n = colbase + wn * 64 + nt * 16 + c;
            int b = m >> 11, t = m & 2047;
            int h = n >> 6, d = n & 63;
            dst[(((size_t)(b * H_ + h) * T_ + t) << 6) + d] = f2bf(acc[mt][nt][i] * scale);
          }
    }
  } else {
#pragma unroll
    for (int mt = 0; mt < 4; ++mt)
#pragma unroll
      for (int nt = 0; nt < 4; ++nt)
#pragma unroll
        for (int i = 0; i < 4; ++i) {
          int m = m0 + wm * 64 + mt * 16 + g * 4 + i;
          int n = n0 + wn * 64 + nt * 16 + c;
          outf[(size_t)m * 1024 + n] = acc[mt][nt][i];
        }
  }
}

// ------------- flash attention, perfectly balanced 2-way k-split -------------
// Grid (bh=64, y=8), XCD = bh&7 (L2 locality, r24-proven). Block y runs TWO half-strips
// totaling exactly 18 iters: (s1=7-h, len 16-2h) + (s2=h, len 2h+2), half=odd, h=y>>1.
// Max-free softmax => partials additive: every segment emits unnormalized bf16 O + f32 l;
// combine() sums the two halves of each strip and normalizes.
#define PV_STEP(PF, KC)                                                                \
  {                                                                                    \
    bf16x8 pf = (PF);                                                                  \
    int dr0 = q32, dr1 = 32 + q32;                                                     \
    bf16x8 v0 = *(const bf16x8*)(sV + dr0 * 128 + 16 * (((KC)*2 + hi) ^ (dr0 & 7)));   \
    bf16x8 v1 = *(const bf16x8*)(sV + dr1 * 128 + 16 * (((KC)*2 + hi) ^ (dr1 & 7)));   \
    oT0 = __builtin_amdgcn_mfma_f32_32x32x16_bf16(v0, pf, oT0, 0, 0, 0);               \
    oT1 = __builtin_amdgcn_mfma_f32_32x32x16_bf16(v1, pf, oT1, 0, 0, 0);               \
  }

__global__ __launch_bounds__(512) void attn(
    const unsigned short* __restrict__ qbp,  // [bh][T][64], pre-scaled by 0.125*log2e
    const unsigned short* __restrict__ kb,   // [bh][T][64]
    const unsigned short* __restrict__ vt,   // [bh][64][T]
    unsigned short* __restrict__ opart,      // [bh*8*2][256][64] bf16 partials
    float* __restrict__ lpart) {             // [bh*8*2][256] f32
  __shared__ __align__(16) char pool[49152];  // 3 slots x (K 8KB + V 8KB); epilogue reuse
  const int tid = threadIdx.x;
  const int wave = tid >> 6, lane = tid & 63;
  const int q32 = lane & 31, hi = lane >> 5;
  const int bh = blockIdx.x;                   // XCD = bh & 7
  const int y = blockIdx.y;
  const int h = y >> 1, odd = y & 1;

  auto stage = [&](int buf, int kt) {
    int r = tid >> 3, s8 = tid & 7;
    gload_lds16(kb + ((size_t)bh * T_ + kt * 64 + r) * 64 + 8 * (s8 ^ (r & 7)),
                pool + buf * 16384 + tid * 16);
    gload_lds16(vt + ((size_t)bh * 64 + r) * T_ + kt * 64 + 8 * (s8 ^ (r & 7)),
                pool + buf * 16384 + 8192 + tid * 16);
  };

#pragma unroll
  for (int seg = 0; seg < 2; ++seg) {
    const int pb  = seg == 0 ? 7 - h : h;
    const int len = seg == 0 ? 16 - 2 * h : 2 * h + 2;   // >= 2 always
    const int k0t = odd * len;
    const int k1t = k0t + len - 1;
    const int pidx = (bh * 8 + pb) * 2 + odd;
    const int q0w = pb * 256 + wave * 32;
    const int dtile = 4 * pb + (wave >> 1);

    bf16x8 qf[4];
#pragma unroll
    for (int dhc = 0; dhc < 4; ++dhc)
      qf[dhc] = *(const bf16x8*)(qbp + ((size_t)bh * T_ + q0w + q32) * 64 + dhc * 16 + hi * 8);

    f32x16 oT0 = {}, oT1 = {};
    float l_run = 0.0f;

    stage(0, k0t);
    stage(1, k0t + 1);
    int sj = 0;
    for (int kt = k0t; kt <= k1t; ++kt) {
      asm volatile("s_waitcnt vmcnt(2)" ::: "memory");
      __builtin_amdgcn_s_barrier();
      asm volatile("" ::: "memory");
      int st2 = sj + 2; if (st2 >= 3) st2 -= 3;
      if (kt + 2 <= k1t) stage(st2, kt + 2);
      if (kt <= dtile) {
        const char* sK = pool + sj * 16384;
        const char* sV = sK + 8192;

        f32x16 st0 = {}, st1 = {};
        __builtin_amdgcn_s_setprio(1);
#pragma unroll
        for (int dhc = 0; dhc < 4; ++dhc) {
          int kr0 = q32, kr1 = 32 + q32;
          bf16x8 k0 = *(const bf16x8*)(sK + kr0 * 128 + 16 * ((dhc * 2 + hi) ^ (kr0 & 7)));
          bf16x8 k1 = *(const bf16x8*)(sK + kr1 * 128 + 16 * ((dhc * 2 + hi) ^ (kr1 & 7)));
          st0 = __builtin_amdgcn_mfma_f32_32x32x16_bf16(k0, qf[dhc], st0, 0, 0, 0);
          st1 = __builtin_amdgcn_mfma_f32_32x32x16_bf16(k1, qf[dhc], st1, 0, 0, 0);
        }
        __builtin_amdgcn_s_setprio(0);

        if (kt == dtile) {  // causal mask on diagonal tile (exp2(-inf) = 0)
          int qg = q0w + q32;
#pragma unroll
          for (int r = 0; r < 16; ++r) {
            int krow = kt * 64 + (r & 3) + 8 * (r >> 2) + 4 * hi;
            if (krow > qg) st0[r] = -INFINITY;
            if (krow + 32 > qg) st1[r] = -INFINITY;
          }
        }

        // max-free softmax: p = 2^s via raw v_exp_f32 (inputs bounded; -inf -> 0)
        float ps0 = 0.0f, ps1 = 0.0f, ps2 = 0.0f, ps3 = 0.0f;
#pragma unroll
        for (int r = 0; r < 16; r += 4) {
          float a0 = __builtin_amdgcn_exp2f(st0[r + 0]); st0[r + 0] = a0; ps0 += a0;
          float a1 = __builtin_amdgcn_exp2f(st0[r + 1]); st0[r + 1] = a1; ps1 += a1;
          float a2 = __builtin_amdgcn_exp2f(st0[r + 2]); st0[r + 2] = a2; ps2 += a2;
          float a3 = __builtin_amdgcn_exp2f(st0[r + 3]); st0[r + 3] = a3; ps3 += a3;
        }
#pragma unroll
        for (int r = 0; r < 16; r += 4) {
          float a0 = __builtin_amdgcn_exp2f(st1[r + 0]); st1[r + 0] = a0; ps0 += a0;
          float a1 = __builtin_amdgcn_exp2f(st1[r + 1]); st1[r + 1] = a1; ps1 += a1;
          float a2 = __builtin_amdgcn_exp2f(st1[r + 2]); st1[r + 2] = a2; ps2 += a2;
          float a3 = __builtin_amdgcn_exp2f(st1[r + 3]); st1[r + 3] = a3; ps3 += a3;
        }
        float ps = (ps0 + ps1) + (ps2 + ps3);
        ps += __shfl_xor(ps, 32);
        l_run += ps;

        __builtin_amdgcn_s_setprio(1);
        PV_STEP(buildP<0>(st0), 0)
        PV_STEP(buildP<8>(st0), 1)
        PV_STEP(buildP<0>(st1), 2)
        PV_STEP(buildP<8>(st1), 3)
        __builtin_amdgcn_s_setprio(0);
      }
      sj = sj + 1; if (sj >= 3) sj -= 3;
    }

    // partial epilogue: unnormalized O -> per-wave LDS transpose -> opart; l -> lpart
    __syncthreads();
    if (hi == 0) lpart[pidx * 256 + wave * 32 + q32] = l_run;
    unsigned short* ep = (unsigned short*)pool + wave * (32 * 72);
#pragma unroll
    for (int r = 0; r < 16; ++r) {
      int d0 = (r & 3) + 8 * (r >> 2) + 4 * hi;
      ep[q32 * 72 + d0]      = f2bf(oT0[r]);
      ep[q32 * 72 + 32 + d0] = f2bf(oT1[r]);
    }
    __syncthreads();
    {
      int q = lane >> 1, half = lane & 1;
      const unsigned short* row = ep + q * 72 + half * 32;
      unsigned short* g = opart + ((size_t)pidx * 256 + wave * 32 + q) * 64 + half * 32;
#pragma unroll
      for (int j = 0; j < 4; ++j)
        *(u16x8*)(g + j * 8) = *(const u16x8*)(row + j * 8);
    }
    if (seg == 0) __syncthreads();   // pool reused by seg2 staging
  }
}

// ------------- combine: O = (OA+OB)/(lA+lB) -> bf16 ao, for all 512 (bh,strip) pairs ----
__global__ __launch_bounds__(256) void combine(
    const unsigned short* __restrict__ opart, const float* __restrict__ lpart,
    unsigned short* __restrict__ ao) {
  int pair = blockIdx.x;              // bh*8 + strip
  int bh = pair >> 3, strip = pair & 7;
  int tid = threadIdx.x;
  int rloc = tid >> 2, dc = tid & 3;  // 64 rows/pass, 16-col chunk
  const unsigned short* A  = opart + ((size_t)(pair * 2 + 0)) * 256 * 64;
  const unsigned short* Bp = opart + ((size_t)(pair * 2 + 1)) * 256 * 64;
  const float* lA = lpart + (pair * 2 + 0) * 256;
  const float* lB = lpart + (pair * 2 + 1) * 256;
  int b = bh >> 4, hh = bh & 15;
#pragma unroll
  for (int rr = 0; rr < 4; ++rr) {
    int row = rr * 64 + rloc;
    float inv = 1.0f / (lA[row] + lB[row]);
    const unsigned short* pa  = A + row * 64 + dc * 16;
    const unsigned short* pbp = Bp + row * 64 + dc * 16;
    u16x8 a0 = *(const u16x8*)pa,  a1 = *(const u16x8*)(pa + 8);
    u16x8 b0 = *(const u16x8*)pbp, b1 = *(const u16x8*)(pbp + 8);
    u16x8 o0, o1;
#pragma unroll
    for (int j = 0; j < 8; ++j) {
      o0[j] = f2bf((bf2f(a0[j]) + bf2f(b0[j])) * inv);
      o1[j] = f2bf((bf2f(a1[j]) + bf2f(b1[j])) * inv);
    }
    int t = strip * 256 + row;
    unsigned short* g = ao + ((size_t)(b * T_ + t)) * 1024 + hh * 64 + dc * 16;
    *(u16x8*)g = o0;
    *(u16x8*)(g + 8) = o1;
  }
}

extern "C" void kernel_launch(void* const* d_in, const int* in_sizes, int n_in,
                              void* d_out, int out_size, void* d_ws, size_t ws_size,
                              hipStream_t stream) {
  const float* x = (const float*)d_in[0];
  const float* w_qkv = (const float*)d_in[1];
  const float* w_out = (const float*)d_in[2];
  float* out = (float*)d_out;

  char* ws = (char*)d_ws;
  size_t off = 0;
  auto alloc = [&](size_t bytes) {
    char* p = ws + off;
    off += (bytes + 255) & ~(size_t)255;
    return p;
  };
  unsigned short* xb    = (unsigned short*)alloc((size_t)M_ * D_ * 2);
  unsigned short* wqkvT = (unsigned short*)alloc((size_t)N3_ * D_ * 2);
  unsigned short* woutT = (unsigned short*)alloc((size_t)D_ * D_ * 2);
  unsigned short* qbuf  = (unsigned short*)alloc((size_t)BH_ * T_ * 64 * 2);
  unsigned short* kbuf  = (unsigned short*)alloc((size_t)BH_ * T_ * 64 * 2);
  unsigned short* vtb   = (unsigned short*)alloc((size_t)BH_ * 64 * T_ * 2);
  unsigned short* opart = (unsigned short*)alloc((size_t)BH_ * 8 * 2 * 256 * 64 * 2);  // 16.8 MB
  float*          lpart = (float*)alloc((size_t)BH_ * 8 * 2 * 256 * 4);                // 1 MB
  unsigned short* ao    = xb;  // reuse: xb dead after QKV GEMM

  hipFuncSetAttribute(reinterpret_cast<const void*>(gemm2b),
                      hipFuncAttributeMaxDynamicSharedMemorySize, 65536);

  prep<<<4096 + 768 + 256, 256, 0, stream>>>(x, xb, w_qkv, wqkvT, w_out, woutT);
  gemm2b<<<dim3(M_ / 128, N3_ / 128), 256, 65536, stream>>>(xb, wqkvT, 0, qbuf, kbuf, vtb, nullptr);
  attn<<<dim3(BH_, 8), 512, 0, stream>>>(qbuf, kbuf, vtb, opart, lpart);
  combine<<<BH_ * 8, 256, 0, stream>>>(opart, lpart, ao);
  gemm2b<<<dim3(M_ / 128, D_ / 128), 256, 65536, stream>>>(ao, woutT, 1, nullptr, nullptr, nullptr, out);
}

// Round 27
// 140.470 us; speedup vs baseline: 1.0800x; 1.0800x over previous
//
#include <hip/hip_runtime.h>

#define B_ 4
#define T_ 2048
#define D_ 1024
#define H_ 16
#define DH_ 64
#define BH_ (B_*H_)   // 64
#define M_ (B_*T_)    // 8192
#define N3_ (3*D_)    // 3072

typedef __attribute__((ext_vector_type(8))) __bf16 bf16x8;
typedef __attribute__((ext_vector_type(4))) float f32x4;
typedef __attribute__((ext_vector_type(16))) float f32x16;
typedef __attribute__((ext_vector_type(8))) unsigned short u16x8;
typedef __attribute__((ext_vector_type(4))) unsigned short u16x4;
typedef int i32x2 __attribute__((ext_vector_type(2)));

__device__ inline void gload_lds16(const void* g, void* l) {
  __builtin_amdgcn_global_load_lds((const __attribute__((address_space(1))) void*)g,
                                   (__attribute__((address_space(3))) void*)l, 16, 0, 0);
}

__device__ inline unsigned short f2bf(float v) {
  __bf16 t = (__bf16)v;
  return *(unsigned short*)&t;
}

__device__ inline unsigned pk2(float lo, float hi2) {
  return (unsigned)f2bf(lo) | ((unsigned)f2bf(hi2) << 16);
}

// Build PV B-fragment (P^T[16k][32q]); permlane32_swap: dst.row1 <-> src.row0 (verified r12).
// NOTE: distinct-value operands only — same-value-both-operands (r15 pairsum) miscomputed.
template<int BASE>
__device__ inline bf16x8 buildP(const f32x16& S) {
  unsigned a = pk2(S[BASE+0], S[BASE+1]);
  unsigned b = pk2(S[BASE+2], S[BASE+3]);
  unsigned c = pk2(S[BASE+4], S[BASE+5]);
  unsigned d = pk2(S[BASE+6], S[BASE+7]);
  i32x2 r0 = __builtin_amdgcn_permlane32_swap((int)a, (int)c, false, false);
  i32x2 r1 = __builtin_amdgcn_permlane32_swap((int)b, (int)d, false, false);
  union { unsigned u[4]; bf16x8 v; } U;
  U.u[0] = (unsigned)r0[0];
  U.u[1] = (unsigned)r1[0];
  U.u[2] = (unsigned)r0[1];
  U.u[3] = (unsigned)r1[1];
  return U.v;
}

// ------------- fused prep: cast x -> bf16 | transpose+cast w_qkv | transpose+cast w_out ----
__global__ void prep(const float* __restrict__ x, unsigned short* __restrict__ xb,
                     const float* __restrict__ wq, unsigned short* __restrict__ wqT,
                     const float* __restrict__ wo, unsigned short* __restrict__ woT) {
  __shared__ unsigned short lds[64][72];
  int bid = blockIdx.x, tid = threadIdx.x;
  if (bid < 4096) {
    int i = bid * 256 + tid;
    const float4* p = (const float4*)(x + (size_t)i * 8);
    float4 a = p[0], b = p[1];
    float v[8] = {a.x, a.y, a.z, a.w, b.x, b.y, b.z, b.w};
    u16x8 r;
#pragma unroll
    for (int j = 0; j < 8; ++j) r[j] = f2bf(v[j]);
    *(u16x8*)(xb + (size_t)i * 8) = r;
    return;
  }
  const float* w;
  unsigned short* wt;
  int n0, k0, Ndim;
  if (bid < 4096 + 768) {
    int b2 = bid - 4096;
    w = wq; wt = wqT; Ndim = N3_;
    n0 = (b2 % 48) * 64; k0 = (b2 / 48) * 64;
  } else {
    int b3 = bid - 4864;
    w = wo; wt = woT; Ndim = D_;
    n0 = (b3 % 16) * 64; k0 = (b3 / 16) * 64;
  }
#pragma unroll
  for (int i = 0; i < 2; ++i) {
    int idx = i * 256 + tid;
    int r = idx >> 3, c8 = idx & 7;
    const float4* src = (const float4*)(w + (size_t)(k0 + r) * Ndim + n0 + c8 * 8);
    float4 a = src[0], b = src[1];
    float v[8] = {a.x, a.y, a.z, a.w, b.x, b.y, b.z, b.w};
#pragma unroll
    for (int j = 0; j < 8; ++j) lds[r][c8 * 8 + j] = f2bf(v[j]);
  }
  __syncthreads();
#pragma unroll
  for (int i = 0; i < 2; ++i) {
    int idx = i * 256 + tid;
    int r = idx >> 3, c8 = idx & 7;
    u16x8 o;
#pragma unroll
    for (int j = 0; j < 8; ++j) o[j] = lds[c8 * 8 + j][r];
    *(u16x8*)(wt + (size_t)(n0 + r) * 1024 + k0 + c8 * 8) = o;
  }
}

// ------------- pipelined GEMM: 128x128 tile, BK=64, 4 waves, 2-slot ring (64KB -> 2 blocks/CU),
// 1-ahead prefetch with counted vmcnt(8) + raw barriers. XCD slab swizzle (A L2-resident).
// K-loop fully unrolled: slot indices/addresses become compile-time constants. ----
__global__ __launch_bounds__(256) void gemm2b(
    const unsigned short* __restrict__ A,
    const unsigned short* __restrict__ BT,
    int epi,
    unsigned short* __restrict__ qb, unsigned short* __restrict__ kb, unsigned short* __restrict__ vtb,
    float* __restrict__ outf) {
  extern __shared__ __align__(16) char lds[];   // 2 * 32768 = 65536 bytes
  const int tid = threadIdx.x;
  const int wave = tid >> 6, lane = tid & 63, g = lane >> 4, c = lane & 15;
  const int wm = wave >> 1, wn = wave & 1;
  int flat = blockIdx.y * gridDim.x + blockIdx.x;
  int xcd = flat & 7, local = flat >> 3;
  int bx = xcd * 8 + (local & 7);   // gridDim.x == 64
  int by = local >> 3;
  const int m0 = bx * 128, n0 = by * 128;

  f32x4 acc[4][4] = {};

  auto stage = [&](int slot, int jj) {
    char* sb = lds + slot * 32768;
#pragma unroll
    for (int i = 0; i < 4; ++i) {
      int idx = i * 256 + tid;
      int r = idx >> 3, s = idx & 7;
      gload_lds16(A + (size_t)(m0 + r) * 1024 + jj * 64 + 8 * (s ^ (r & 7)),
                  sb + idx * 16);
    }
#pragma unroll
    for (int i = 0; i < 4; ++i) {
      int idx = i * 256 + tid;
      int r = idx >> 3, s = idx & 7;
      gload_lds16(BT + (size_t)(n0 + r) * 1024 + jj * 64 + 8 * (s ^ (r & 7)),
                  sb + 16384 + idx * 16);
    }
  };

  stage(0, 0);
#pragma unroll
  for (int j = 0; j < 16; ++j) {
    if (j < 15) {
      stage((j + 1) & 1, j + 1);
      asm volatile("s_waitcnt vmcnt(8)" ::: "memory");
    } else {
      asm volatile("s_waitcnt vmcnt(0)" ::: "memory");
    }
    __builtin_amdgcn_s_barrier();
    asm volatile("" ::: "memory");

    const char* sA = lds + (j & 1) * 32768;
    const char* sB = sA + 16384;
#pragma unroll
    for (int kc = 0; kc < 2; ++kc) {
      bf16x8 af[4], bf[4];
#pragma unroll
      for (int mt = 0; mt < 4; ++mt) {
        int r = wm * 64 + mt * 16 + c;
        af[mt] = *(const bf16x8*)(sA + r * 128 + 16 * ((kc * 4 + g) ^ (r & 7)));
      }
#pragma unroll
      for (int nt = 0; nt < 4; ++nt) {
        int r = wn * 64 + nt * 16 + c;
        bf[nt] = *(const bf16x8*)(sB + r * 128 + 16 * ((kc * 4 + g) ^ (r & 7)));
      }
      __builtin_amdgcn_s_setprio(1);
#pragma unroll
      for (int mt = 0; mt < 4; ++mt)
#pragma unroll
        for (int nt = 0; nt < 4; ++nt)
          acc[mt][nt] = __builtin_amdgcn_mfma_f32_16x16x32_bf16(af[mt], bf[nt], acc[mt][nt], 0, 0, 0);
      __builtin_amdgcn_s_setprio(0);
    }

    __builtin_amdgcn_s_barrier();
    asm volatile("" ::: "memory");
  }

  if (epi == 0) {
    int which = n0 >> 10;  // 0:q 1:k 2:v (uniform: 128 | 1024)
    int colbase = n0 - (which << 10);
    if (which == 2) {
#pragma unroll
      for (int mt = 0; mt < 4; ++mt)
#pragma unroll
        for (int nt = 0; nt < 4; ++nt) {
          int m = m0 + wm * 64 + mt * 16 + g * 4;
          int n = colbase + wn * 64 + nt * 16 + c;
          int b = m >> 11, t = m & 2047;
          int h = n >> 6, d = n & 63;
          u16x4 pk;
#pragma unroll
          for (int i = 0; i < 4; ++i) pk[i] = f2bf(acc[mt][nt][i]);
          *(u16x4*)(vtb + ((size_t)(b * H_ + h) * 64 + d) * T_ + t) = pk;
        }
    } else {
      unsigned short* dst = which == 0 ? qb : kb;
      float scale = which == 0 ? 0.18033688011112042f : 1.0f;  // (1/8)*log2(e)
#pragma unroll
      for (int mt = 0; mt < 4; ++mt)
#pragma unroll
        for (int nt = 0; nt < 4; ++nt)
#pragma unroll
          for (int i = 0; i < 4; ++i) {
            int m = m0 + wm * 64 + mt * 16 + g * 4 + i;
            int n = colbase + wn * 64 + nt * 16 + c;
            int b = m >> 11, t = m & 2047;
            int h = n >> 6, d = n & 63;
            dst[(((size_t)(b * H_ + h) * T_ + t) << 6) + d] = f2bf(acc[mt][nt][i] * scale);
          }
    }
  } else {
#pragma unroll
    for (int mt = 0; mt < 4; ++mt)
#pragma unroll
      for (int nt = 0; nt < 4; ++nt)
#pragma unroll
        for (int i = 0; i < 4; ++i) {
          int m = m0 + wm * 64 + mt * 16 + g * 4 + i;
          int n = n0 + wn * 64 + nt * 16 + c;
          outf[(size_t)m * 1024 + n] = acc[mt][nt][i];
        }
  }
}

// ------------- flash attention: 8 waves x 32 q-rows, 32x32 MFMA, max-free softmax,
// 3-slot LDS ring, counted vmcnt(2), raw-exp2. Grid (bh, slot): XCD = bh&7 so each XCD
// serves 8 heads (8MB K/V working set -> L2 reuse across pb-blocks).
// Pairing: CU hosts (bh, y) and (bh, y+4); pb = y<4 ? y : 11-y -> pairs sum to 7 (36 units/CU).
#define PV_STEP(PF, KC)                                                                \
  {                                                                                    \
    bf16x8 pf = (PF);                                                                  \
    int dr0 = q32, dr1 = 32 + q32;                                                     \
    bf16x8 v0 = *(const bf16x8*)(sV + dr0 * 128 + 16 * (((KC)*2 + hi) ^ (dr0 & 7)));   \
    bf16x8 v1 = *(const bf16x8*)(sV + dr1 * 128 + 16 * (((KC)*2 + hi) ^ (dr1 & 7)));   \
    oT0 = __builtin_amdgcn_mfma_f32_32x32x16_bf16(v0, pf, oT0, 0, 0, 0);               \
    oT1 = __builtin_amdgcn_mfma_f32_32x32x16_bf16(v1, pf, oT1, 0, 0, 0);               \
  }

__global__ __launch_bounds__(512) void attn(
    const unsigned short* __restrict__ qbp,  // [bh][T][64], pre-scaled by 0.125*log2e
    const unsigned short* __restrict__ kb,   // [bh][T][64]
    const unsigned short* __restrict__ vt,   // [bh][64][T]
    unsigned short* __restrict__ ao) {       // [M][1024] bf16
  __shared__ __align__(16) char pool[49152];  // 3 slots x (K 8KB + V 8KB); epilogue reuse (36KB)
  const int tid = threadIdx.x;
  const int wave = tid >> 6, lane = tid & 63;
  const int q32 = lane & 31, hi = lane >> 5;
  const int bh = blockIdx.x;                   // XCD = bh & 7
  const int y = blockIdx.y;
  const int pb = (y < 4) ? y : 11 - y;         // complementary pairs (y, y+4) sum to 7
  const int q0w = pb * 256 + wave * 32;
  const int kmax = 4 * pb + 3;
  const int dtile = 4 * pb + (wave >> 1);

  bf16x8 qf[4];
#pragma unroll
  for (int dhc = 0; dhc < 4; ++dhc)
    qf[dhc] = *(const bf16x8*)(qbp + ((size_t)bh * T_ + q0w + q32) * 64 + dhc * 16 + hi * 8);

  f32x16 oT0 = {}, oT1 = {};
  float l_run = 0.0f;

  auto stage = [&](int buf, int kt) {
    int r = tid >> 3, s8 = tid & 7;
    gload_lds16(kb + ((size_t)bh * T_ + kt * 64 + r) * 64 + 8 * (s8 ^ (r & 7)),
                pool + buf * 16384 + tid * 16);
    gload_lds16(vt + ((size_t)bh * 64 + r) * T_ + kt * 64 + 8 * (s8 ^ (r & 7)),
                pool + buf * 16384 + 8192 + tid * 16);
  };

  stage(0, 0);
  stage(1, 1);
  int sj = 0;
  for (int kt = 0; kt <= kmax; ++kt) {
    asm volatile("s_waitcnt vmcnt(2)" ::: "memory");
    __builtin_amdgcn_s_barrier();
    asm volatile("" ::: "memory");
    int st2 = sj + 2; if (st2 >= 3) st2 -= 3;
    if (kt + 2 <= kmax) stage(st2, kt + 2);
    if (kt <= dtile) {
      const char* sK = pool + sj * 16384;
      const char* sV = sK + 8192;

      f32x16 st0 = {}, st1 = {};
      __builtin_amdgcn_s_setprio(1);
#pragma unroll
      for (int dhc = 0; dhc < 4; ++dhc) {
        int kr0 = q32, kr1 = 32 + q32;
        bf16x8 k0 = *(const bf16x8*)(sK + kr0 * 128 + 16 * ((dhc * 2 + hi) ^ (kr0 & 7)));
        bf16x8 k1 = *(const bf16x8*)(sK + kr1 * 128 + 16 * ((dhc * 2 + hi) ^ (kr1 & 7)));
        st0 = __builtin_amdgcn_mfma_f32_32x32x16_bf16(k0, qf[dhc], st0, 0, 0, 0);
        st1 = __builtin_amdgcn_mfma_f32_32x32x16_bf16(k1, qf[dhc], st1, 0, 0, 0);
      }
      __builtin_amdgcn_s_setprio(0);

      if (kt == dtile) {  // causal mask on diagonal tile (exp2(-inf) = 0)
        int qg = q0w + q32;
#pragma unroll
        for (int r = 0; r < 16; ++r) {
          int krow = kt * 64 + (r & 3) + 8 * (r >> 2) + 4 * hi;
          if (krow > qg) st0[r] = -INFINITY;
          if (krow + 32 > qg) st1[r] = -INFINITY;
        }
      }

      // max-free softmax: p = 2^s via raw v_exp_f32 (inputs bounded; -inf -> 0)
      float ps0 = 0.0f, ps1 = 0.0f, ps2 = 0.0f, ps3 = 0.0f;
#pragma unroll
      for (int r = 0; r < 16; r += 4) {
        float a0 = __builtin_amdgcn_exp2f(st0[r + 0]); st0[r + 0] = a0; ps0 += a0;
        float a1 = __builtin_amdgcn_exp2f(st0[r + 1]); st0[r + 1] = a1; ps1 += a1;
        float a2 = __builtin_amdgcn_exp2f(st0[r + 2]); st0[r + 2] = a2; ps2 += a2;
        float a3 = __builtin_amdgcn_exp2f(st0[r + 3]); st0[r + 3] = a3; ps3 += a3;
      }
#pragma unroll
      for (int r = 0; r < 16; r += 4) {
        float a0 = __builtin_amdgcn_exp2f(st1[r + 0]); st1[r + 0] = a0; ps0 += a0;
        float a1 = __builtin_amdgcn_exp2f(st1[r + 1]); st1[r + 1] = a1; ps1 += a1;
        float a2 = __builtin_amdgcn_exp2f(st1[r + 2]); st1[r + 2] = a2; ps2 += a2;
        float a3 = __builtin_amdgcn_exp2f(st1[r + 3]); st1[r + 3] = a3; ps3 += a3;
      }
      float ps = (ps0 + ps1) + (ps2 + ps3);
      ps += __shfl_xor(ps, 32);
      l_run += ps;

      __builtin_amdgcn_s_setprio(1);
      PV_STEP(buildP<0>(st0), 0)
      PV_STEP(buildP<8>(st0), 1)
      PV_STEP(buildP<0>(st1), 2)
      PV_STEP(buildP<8>(st1), 3)
      __builtin_amdgcn_s_setprio(0);
    }
    sj = sj + 1; if (sj >= 3) sj -= 3;
  }

  __syncthreads();
  unsigned short* ep = (unsigned short*)pool + wave * (32 * 72);
  float inv_l = 1.0f / l_run;
#pragma unroll
  for (int r = 0; r < 16; ++r) {
    int d0 = (r & 3) + 8 * (r >> 2) + 4 * hi;
    ep[q32 * 72 + d0]      = f2bf(oT0[r] * inv_l);
    ep[q32 * 72 + 32 + d0] = f2bf(oT1[r] * inv_l);
  }
  __syncthreads();
  {
    int q = lane >> 1, half = lane & 1;
    int t = q0w + q;
    int b = bh >> 4, h = bh & 15;
    const unsigned short* row = ep + q * 72 + half * 32;
    unsigned short* g = ao + ((size_t)(b * T_ + t)) * 1024 + h * 64 + half * 32;
#pragma unroll
    for (int j = 0; j < 4; ++j)
      *(u16x8*)(g + j * 8) = *(const u16x8*)(row + j * 8);
  }
}

extern "C" void kernel_launch(void* const* d_in, const int* in_sizes, int n_in,
                              void* d_out, int out_size, void* d_ws, size_t ws_size,
                              hipStream_t stream) {
  const float* x = (const float*)d_in[0];
  const float* w_qkv = (const float*)d_in[1];
  const float* w_out = (const float*)d_in[2];
  float* out = (float*)d_out;

  char* ws = (char*)d_ws;
  size_t off = 0;
  auto alloc = [&](size_t bytes) {
    char* p = ws + off;
    off += (bytes + 255) & ~(size_t)255;
    return p;
  };
  unsigned short* xb    = (unsigned short*)alloc((size_t)M_ * D_ * 2);
  unsigned short* wqkvT = (unsigned short*)alloc((size_t)N3_ * D_ * 2);
  unsigned short* woutT = (unsigned short*)alloc((size_t)D_ * D_ * 2);
  unsigned short* qbuf  = (unsigned short*)alloc((size_t)BH_ * T_ * 64 * 2);
  unsigned short* kbuf  = (unsigned short*)alloc((size_t)BH_ * T_ * 64 * 2);
  unsigned short* vtb   = (unsigned short*)alloc((size_t)BH_ * 64 * T_ * 2);
  unsigned short* ao    = xb;  // reuse: xb dead after QKV GEMM

  hipFuncSetAttribute(reinterpret_cast<const void*>(gemm2b),
                      hipFuncAttributeMaxDynamicSharedMemorySize, 65536);

  prep<<<4096 + 768 + 256, 256, 0, stream>>>(x, xb, w_qkv, wqkvT, w_out, woutT);
  gemm2b<<<dim3(M_ / 128, N3_ / 128), 256, 65536, stream>>>(xb, wqkvT, 0, qbuf, kbuf, vtb, nullptr);
  attn<<<dim3(BH_, T_ / 256), 512, 0, stream>>>(qbuf, kbuf, vtb, ao);
  gemm2b<<<dim3(M_ / 128, D_ / 128), 256, 65536, stream>>>(ao, woutT, 1, nullptr, nullptr, nullptr, out);
}